// Round 2
// baseline (34151.331 us; speedup 1.0000x reference)
//
#include <hip/hip_runtime.h>
#include <hip/hip_bf16.h>

typedef unsigned short u16;
typedef unsigned int u32;

#define T_ 128
#define B_ 256
#define H_ 850
#define BH (B_ * H_)      // 217600
#define KPN 864           // padded K for node gemms (850 -> 864)
#define KP1 1728          // padded K for stage1 (1700 -> 1728)

typedef __attribute__((ext_vector_type(8))) short short8;
typedef __attribute__((ext_vector_type(4))) float floatx4;

// ARCH pairs: (0,0),(0,1),(1,2),(1,3),(2,0),(2,1),(3,2),(4,3)
__device__ __constant__ int PRED[8]  = {0, 0, 1, 1, 2, 2, 3, 4};
__device__ __constant__ int ACTID[8] = {0, 1, 2, 3, 0, 1, 2, 3};

__device__ __forceinline__ float sigf(float x) {
    return 1.f / (1.f + __expf(-x));
}
__device__ __forceinline__ float actf(int a, float x) {
    if (a == 0) { // tanh, saturates safely at +-1
        float e = __expf(2.f * x);
        return 1.f - 2.f / (e + 1.f);
    }
    if (a == 1) return x > 0.f ? x : 0.f;
    if (a == 2) return sigf(x);
    return x;
}
// split fp32 into bf16 hi + bf16 lo  (x ~= hi + lo, residual ~2^-18 rel)
__device__ __forceinline__ void split2(float x, u16& hi, u16& lo) {
    __hip_bfloat16 h = __float2bfloat16(x);
    float hf = __bfloat162float(h);
    __hip_bfloat16 l = __float2bfloat16(x - hf);
    hi = *reinterpret_cast<u16*>(&h);
    lo = *reinterpret_cast<u16*>(&l);
}

// ---- weight transpose + hi/lo split: W[k][n] fp32 -> WhT[n][kp], WlT[n][kp] bf16 ----
// z=0: W0 [1700,1700] -> [1700][1728]; z=1..8: Ws[i] [850,1700] -> [1700][864]
__global__ __launch_bounds__(256) void transpose_w(
    const float* __restrict__ W0s, const float* __restrict__ WSs,
    u16* __restrict__ WhT0, u16* __restrict__ WlT0,
    u16* __restrict__ WhTS, u16* __restrict__ WlTS)
{
    const int z = blockIdx.z;
    const float* src; u16 *dh, *dl; int Ksrc, Kp;
    if (z == 0) { src = W0s; dh = WhT0; dl = WlT0; Ksrc = 1700; Kp = KP1; }
    else {
        src = WSs + (size_t)(z - 1) * 850 * 1700;
        dh = WhTS + (size_t)(z - 1) * 1700 * KPN;
        dl = WlTS + (size_t)(z - 1) * 1700 * KPN;
        Ksrc = 850; Kp = KPN;
    }
    const int k0 = blockIdx.x * 64;
    if (k0 >= Kp) return;
    const int n0 = blockIdx.y * 64;

    __shared__ float tile[64][65];
    const int t = threadIdx.x;

    // read phase: coalesced along n.  tile[dk][dn] = W[k0+dk][n0+dn]
    const int cn = t & 63;
    const int rb = (t >> 6) * 16;
#pragma unroll
    for (int j = 0; j < 16; j++) {
        const int k = k0 + rb + j;
        const int n = n0 + cn;
        float v = 0.f;
        if (k < Ksrc && n < 1700) v = src[(size_t)k * 1700 + n];
        tile[rb + j][cn] = v;
    }
    __syncthreads();

    // write phase: coalesced along k, u32 pairs
    const int r  = t >> 2;          // n within tile
    const int c0 = (t & 3) * 16;    // k offset within tile
    const int n = n0 + r;
    if (n < 1700) {
#pragma unroll
        for (int j = 0; j < 16; j += 2) {
            const int kk = k0 + c0 + j;
            if (kk < Kp) {
                u16 h0, l0, h1, l1;
                split2(tile[c0 + j][r],     h0, l0);
                split2(tile[c0 + j + 1][r], h1, l1);
                *(u32*)(dh + (size_t)n * Kp + kk) = (u32)h0 | ((u32)h1 << 16);
                *(u32*)(dl + (size_t)n * Kp + kk) = (u32)l0 | ((u32)l1 << 16);
            }
        }
    }
}

// ---- init: copy fp32 hidden into state buffer ----
__global__ __launch_bounds__(256) void init_kern(
    const float* __restrict__ HID, float* __restrict__ HF)
{
    const int i = blockIdx.x * 256 + threadIdx.x;
    HF[i] = HID[i];
}

__device__ __forceinline__ float loadA(const float* __restrict__ A0,
                                       const float* __restrict__ A1,
                                       int aoff, int kg, bool concat)
{
    if (concat) {
        if (kg < 850)  return A0[aoff + kg];
        if (kg < 1700) return A1[aoff + kg - 850];
        return 0.f;
    }
    return (kg < 850) ? A0[aoff + kg] : 0.f;
}

// ---- fused split-bf16 GEMM + cell update: out = S + sigmoid(A@Wc) * (act(A@Wh) - S) ----
// Wh/Wl are transposed weights [1700 n-rows (0..849 = c part, 850..1699 = h part)][Kp]
template <bool CONCAT>
__device__ __forceinline__ void gemm_core(
    const float* __restrict__ A0, const float* __restrict__ A1,
    const u16* __restrict__ Wh, const u16* __restrict__ Wl, const int Kp,
    const float* __restrict__ S, float* __restrict__ OF, const int act)
{
    __shared__ __align__(16) u16 Ahs[64][40];
    __shared__ __align__(16) u16 Als[64][40];
    __shared__ __align__(16) u16 Whs[2][64][40];
    __shared__ __align__(16) u16 Wls[2][64][40];

    const int tid  = threadIdx.x;
    const int wave = tid >> 6;
    const int lane = tid & 63;
    const int m0 = blockIdx.x * 64;
    const int nb = blockIdx.y * 64;

    floatx4 accC[4], accH[4];
#pragma unroll
    for (int i = 0; i < 4; i++) {
        accC[i] = (floatx4){0.f, 0.f, 0.f, 0.f};
        accH[i] = (floatx4){0.f, 0.f, 0.f, 0.f};
    }

    // A staging: 64 rows x 32 k; thread handles 8 consecutive k of one row
    const int ar = tid >> 2;
    const int ak = (tid & 3) << 3;
    const int aoff = (m0 + ar) * H_;

    // W staging: 2 parts x 64 rows x 32 k; thread handles 16 k of one row (hi+lo)
    const int wp = tid >> 7;
    const int wr = (tid & 127) >> 1;
    const int wk = (tid & 1) << 4;
    int wrow = (wp ? 850 : 0) + nb + wr;
    if (wrow > 1699) wrow = 1699;   // clamped rows load valid data, never stored
    const u16* whp = Wh + (size_t)wrow * Kp;
    const u16* wlp = Wl + (size_t)wrow * Kp;

    const int mr  = (wave << 4) + (lane & 15);
    const int kq  = (lane >> 4) << 3;
    const int l15 = lane & 15;

    for (int kp = 0; kp < Kp; kp += 32) {
        // A: load fp32, split into hi/lo pairs
        u32 ph[4], pl[4];
#pragma unroll
        for (int jj = 0; jj < 4; jj++) {
            const int kg = kp + ak + (jj << 1);
            const float v0 = loadA(A0, A1, aoff, kg,     CONCAT);
            const float v1 = loadA(A0, A1, aoff, kg + 1, CONCAT);
            u16 h0, l0, h1, l1;
            split2(v0, h0, l0);
            split2(v1, h1, l1);
            ph[jj] = (u32)h0 | ((u32)h1 << 16);
            pl[jj] = (u32)l0 | ((u32)l1 << 16);
        }
        // W: vector loads of pre-split transposed weights
        const uint4 wh0 = *(const uint4*)(whp + kp + wk);
        const uint4 wh1 = *(const uint4*)(whp + kp + wk + 8);
        const uint4 wl0 = *(const uint4*)(wlp + kp + wk);
        const uint4 wl1 = *(const uint4*)(wlp + kp + wk + 8);

        *(uint4*)&Ahs[ar][ak]          = make_uint4(ph[0], ph[1], ph[2], ph[3]);
        *(uint4*)&Als[ar][ak]          = make_uint4(pl[0], pl[1], pl[2], pl[3]);
        *(uint4*)&Whs[wp][wr][wk]      = wh0;
        *(uint4*)&Whs[wp][wr][wk + 8]  = wh1;
        *(uint4*)&Wls[wp][wr][wk]      = wl0;
        *(uint4*)&Wls[wp][wr][wk + 8]  = wl1;
        __syncthreads();

        const short8 ah = *(const short8*)&Ahs[mr][kq];
        const short8 al = *(const short8*)&Als[mr][kq];
#pragma unroll
        for (int ns = 0; ns < 4; ns++) {
            const int nr = (ns << 4) + l15;
            const short8 bhc = *(const short8*)&Whs[0][nr][kq];
            const short8 blc = *(const short8*)&Wls[0][nr][kq];
            const short8 bhh = *(const short8*)&Whs[1][nr][kq];
            const short8 blh = *(const short8*)&Wls[1][nr][kq];
            accC[ns] = __builtin_amdgcn_mfma_f32_16x16x32_bf16(ah, bhc, accC[ns], 0, 0, 0);
            accC[ns] = __builtin_amdgcn_mfma_f32_16x16x32_bf16(al, bhc, accC[ns], 0, 0, 0);
            accC[ns] = __builtin_amdgcn_mfma_f32_16x16x32_bf16(ah, blc, accC[ns], 0, 0, 0);
            accH[ns] = __builtin_amdgcn_mfma_f32_16x16x32_bf16(ah, bhh, accH[ns], 0, 0, 0);
            accH[ns] = __builtin_amdgcn_mfma_f32_16x16x32_bf16(al, bhh, accH[ns], 0, 0, 0);
            accH[ns] = __builtin_amdgcn_mfma_f32_16x16x32_bf16(ah, blh, accH[ns], 0, 0, 0);
        }
        __syncthreads();
    }

    // epilogue: D row = (lane>>4)*4 + reg, col = lane&15  [m89-verified layout]
    const int row0 = m0 + (wave << 4) + ((lane >> 4) << 2);
    const int colb = nb + l15;
#pragma unroll
    for (int ns = 0; ns < 4; ns++) {
        const int col = colb + (ns << 4);
        if (col < H_) {
#pragma unroll
            for (int r = 0; r < 4; r++) {
                const int off = (row0 + r) * H_ + col;
                const float sp = S[off];
                const float hv = actf(act, accH[ns][r]);
                OF[off] = sp + sigf(accC[ns][r]) * (hv - sp);
            }
        }
    }
}

// stage1: s0 from [x_t, h] @ W0  (act = tanh, S = h)
__global__ __launch_bounds__(256) void stage1_kern(
    const float* __restrict__ X, const float* __restrict__ HF,
    const u16* __restrict__ WhT0, const u16* __restrict__ WlT0,
    float* __restrict__ SF)
{
    gemm_core<true>(X, HF, WhT0, WlT0, KP1, HF, SF, 0);
}

// node stage: node = base + blockIdx.z
__global__ __launch_bounds__(256) void node_kern(
    const u16* __restrict__ WhTS, const u16* __restrict__ WlTS,
    float* __restrict__ SF, int base)
{
    const int node = base + blockIdx.z;
    const int pred = PRED[node];
    gemm_core<false>(SF + (size_t)pred * BH, nullptr,
                     WhTS + (size_t)node * 1700 * KPN,
                     WlTS + (size_t)node * 1700 * KPN, KPN,
                     SF + (size_t)pred * BH,
                     SF + (size_t)(node + 1) * BH,
                     ACTID[node]);
}

// finalize: h = mean(s1..s8); write state and output row(s), all fp32
__global__ __launch_bounds__(256) void finalize_kern(
    const float* __restrict__ SF, float* __restrict__ HF,
    float* __restrict__ OUT, float* __restrict__ OUT2)
{
    const int i = blockIdx.x * 256 + threadIdx.x;
    float s = 0.f;
#pragma unroll
    for (int j = 1; j <= 8; j++) s += SF[(size_t)j * BH + i];
    s *= 0.125f;
    HF[i] = s;
    OUT[i] = s;
    if (OUT2) OUT2[i] = s;
}

extern "C" void kernel_launch(void* const* d_in, const int* in_sizes, int n_in,
                              void* d_out, int out_size, void* d_ws, size_t ws_size,
                              hipStream_t stream) {
    const float* X   = (const float*)d_in[0];  // [128, 256, 850] fp32
    const float* HID = (const float*)d_in[1];  // [1, 256, 850]   fp32
    const float* W0  = (const float*)d_in[2];  // [1700, 1700]    fp32
    const float* WS  = (const float*)d_in[3];  // [8, 850, 1700]  fp32

    // workspace layout (bytes): hi/lo transposed weights + fp32 states
    u16*   WhT0 = (u16*)d_ws;                               // 1700*1728
    u16*   WlT0 = WhT0 + (size_t)1700 * KP1;                // 1700*1728
    u16*   WhTS = WlT0 + (size_t)1700 * KP1;                // 8*1700*864
    u16*   WlTS = WhTS + (size_t)8 * 1700 * KPN;            // 8*1700*864
    float* SF   = (float*)(WlTS + (size_t)8 * 1700 * KPN);  // 9 * BH (s0..s8)
    float* HF   = SF + (size_t)9 * BH;                      // BH

    float* OUT = (float*)d_out;

    // per-launch prep (ws is re-poisoned before every call)
    transpose_w<<<dim3(27, 27, 9), 256, 0, stream>>>(W0, WS, WhT0, WlT0, WhTS, WlTS);
    init_kern<<<850, 256, 0, stream>>>(HID, HF);

    const dim3 blk(256);
    for (int t = 0; t < T_; t++) {
        stage1_kern<<<dim3(4, 14, 1), blk, 0, stream>>>(
            X + (size_t)t * BH, HF, WhT0, WlT0, SF);
        node_kern<<<dim3(4, 14, 2), blk, 0, stream>>>(WhTS, WlTS, SF, 0); // nodes 0,1
        node_kern<<<dim3(4, 14, 4), blk, 0, stream>>>(WhTS, WlTS, SF, 2); // nodes 2..5
        node_kern<<<dim3(4, 14, 2), blk, 0, stream>>>(WhTS, WlTS, SF, 6); // nodes 6,7
        finalize_kern<<<850, 256, 0, stream>>>(
            SF, HF, OUT + (size_t)t * BH,
            (t == T_ - 1) ? (OUT + (size_t)T_ * BH) : (float*)nullptr);
    }
}

// Round 3
// 25941.287 us; speedup vs baseline: 1.3165x; 1.3165x over previous
//
#include <hip/hip_runtime.h>
#include <hip/hip_bf16.h>

typedef unsigned short u16;
typedef unsigned int u32;
typedef __attribute__((ext_vector_type(8))) short short8;
typedef __attribute__((ext_vector_type(16))) float floatx16;

#define T_ 128
#define B_ 256
#define H_ 850
#define BH (B_ * H_)          // 217600
#define SP 864                // padded K / plane column stride
#define PS (B_ * SP)          // state plane elems (221184)
#define WMS (1700 * SP)       // one transposed weight matrix elems

// ARCH pairs: (0,0),(0,1),(1,2),(1,3),(2,0),(2,1),(3,2),(4,3)
__device__ __constant__ int PRED[8]  = {0, 0, 1, 1, 2, 2, 3, 4};
__device__ __constant__ int ACTID[8] = {0, 1, 2, 3, 0, 1, 2, 3};

__device__ __forceinline__ float sigf(float x) { return 1.f / (1.f + __expf(-x)); }
__device__ __forceinline__ float actf(int a, float x) {
    if (a == 0) { float e = __expf(2.f * x); return 1.f - 2.f / (e + 1.f); } // tanh
    if (a == 1) return x > 0.f ? x : 0.f;
    if (a == 2) return sigf(x);
    return x;
}
__device__ __forceinline__ float b2f(u16 u) {
    return __uint_as_float(((u32)u) << 16);   // exact bf16 -> f32
}
__device__ __forceinline__ void split2(float x, u16& hi, u16& lo) {
    __hip_bfloat16 h = __float2bfloat16(x);
    float hf = __bfloat162float(h);
    __hip_bfloat16 l = __float2bfloat16(x - hf);
    hi = reinterpret_cast<u16&>(h);
    lo = reinterpret_cast<u16&>(l);
}

// ---- transpose + split: 10 matrices, each src [850 k][1700 n] -> WT [1700 n][864 k] hi/lo ----
// z=0: W0 rows 0..849 (x-part); z=1: W0 rows 850..1699 (h-part); z=2..9: Ws[z-2]
__global__ __launch_bounds__(256) void transpose_w(
    const float* __restrict__ W0, const float* __restrict__ WS,
    u16* __restrict__ WH, u16* __restrict__ WL)
{
    const int z = blockIdx.z;
    const float* src = (z == 0) ? W0 : (z == 1) ? (W0 + (size_t)850 * 1700)
                       : (WS + (size_t)(z - 2) * 850 * 1700);
    u16* dh = WH + (size_t)z * WMS;
    u16* dl = WL + (size_t)z * WMS;
    const int k0 = blockIdx.x * 64;   // 14 blocks -> up to 896, guarded
    const int n0 = blockIdx.y * 64;   // 27 blocks -> up to 1728, guarded

    __shared__ float tile[64][65];
    const int t = threadIdx.x;
    const int cn = t & 63;
    const int rb = (t >> 6) * 16;
#pragma unroll
    for (int j = 0; j < 16; j++) {
        const int k = k0 + rb + j;
        const int n = n0 + cn;
        float v = 0.f;
        if (k < 850 && n < 1700) v = src[(size_t)k * 1700 + n];
        tile[rb + j][cn] = v;
    }
    __syncthreads();
    const int r  = t >> 2;
    const int c0 = (t & 3) * 16;
    const int n = n0 + r;
    if (n < 1700) {
#pragma unroll
        for (int j = 0; j < 16; j += 2) {
            const int kk = k0 + c0 + j;
            if (kk < SP) {
                u16 h0, l0, h1, l1;
                split2(tile[c0 + j][r],     h0, l0);
                split2(tile[c0 + j + 1][r], h1, l1);
                *(u32*)(dh + (size_t)n * SP + kk) = (u32)h0 | ((u32)h1 << 16);
                *(u32*)(dl + (size_t)n * SP + kk) = (u32)l0 | ((u32)l1 << 16);
            }
        }
    }
}

// ---- init: split fp32 hidden into plane 9 (hi/lo), zero pad cols ----
__global__ __launch_bounds__(256) void init_kern(
    const float* __restrict__ HID, u16* __restrict__ SH, u16* __restrict__ SL)
{
    const int idx = blockIdx.x * 256 + threadIdx.x;   // over PS
    const int row = idx / SP, col = idx % SP;
    float v = (col < H_) ? HID[row * H_ + col] : 0.f;
    u16 hi, lo; split2(v, hi, lo);
    SH[9 * PS + idx] = hi;
    SL[9 * PS + idx] = lo;
}

// ---- zero the pad columns of state planes 0..8 (ws is re-poisoned every call) ----
__global__ __launch_bounds__(256) void zpad_kern(u16* __restrict__ SH, u16* __restrict__ SL)
{
    const int idx = blockIdx.x * 256 + threadIdx.x;   // 9*256*14 = 32256
    if (idx >= 9 * B_ * 14) return;
    const int p = idx / (B_ * 14);
    const int rem = idx % (B_ * 14);
    const int row = rem / 14;
    const int c = H_ + rem % 14;
    const size_t off = (size_t)p * PS + row * SP + c;
    SH[off] = 0; SL[off] = 0;
}

// ---- K-loop over bf16 hi/lo planes (no LDS, direct fragment gathers) ----
__device__ __forceinline__ void kloop_planes(
    const u16* __restrict__ ah, const u16* __restrict__ al,
    const u16* __restrict__ wh, const u16* __restrict__ wl,
    int m0, int rc, int rh, int r31, int seg,
    floatx16& accC, floatx16& accH)
{
    const u16* ap  = ah + (size_t)(m0 + r31) * SP + seg;
    const u16* alp = al + (size_t)(m0 + r31) * SP + seg;
    const u16* wch = wh + (size_t)rc * SP + seg;
    const u16* wcl = wl + (size_t)rc * SP + seg;
    const u16* whh = wh + (size_t)rh * SP + seg;
    const u16* whl = wl + (size_t)rh * SP + seg;
#pragma unroll 4
    for (int kp = 0; kp < SP; kp += 16) {
        const short8 a_h = *(const short8*)(ap  + kp);
        const short8 a_l = *(const short8*)(alp + kp);
        const short8 bch = *(const short8*)(wch + kp);
        const short8 bcl = *(const short8*)(wcl + kp);
        const short8 bhh = *(const short8*)(whh + kp);
        const short8 bhl = *(const short8*)(whl + kp);
        accC = __builtin_amdgcn_mfma_f32_32x32x16_bf16(a_h, bch, accC, 0, 0, 0);
        accH = __builtin_amdgcn_mfma_f32_32x32x16_bf16(a_h, bhh, accH, 0, 0, 0);
        accC = __builtin_amdgcn_mfma_f32_32x32x16_bf16(a_l, bch, accC, 0, 0, 0);
        accH = __builtin_amdgcn_mfma_f32_32x32x16_bf16(a_l, bhh, accH, 0, 0, 0);
        accC = __builtin_amdgcn_mfma_f32_32x32x16_bf16(a_h, bcl, accC, 0, 0, 0);
        accH = __builtin_amdgcn_mfma_f32_32x32x16_bf16(a_h, bhl, accH, 0, 0, 0);
    }
}

// ---- K-loop over fp32 X with in-register split (stage1 x-part) ----
__device__ __forceinline__ void kloop_x(
    const float* __restrict__ X,
    const u16* __restrict__ wh, const u16* __restrict__ wl,
    int m0, int rc, int rh, int r31, int seg,
    floatx16& accC, floatx16& accH)
{
    const float* xr = X + (size_t)(m0 + r31) * H_;
    const u16* wch = wh + (size_t)rc * SP + seg;
    const u16* wcl = wl + (size_t)rc * SP + seg;
    const u16* whh = wh + (size_t)rh * SP + seg;
    const u16* whl = wl + (size_t)rh * SP + seg;
#pragma unroll 2
    for (int kp = 0; kp < SP; kp += 16) {
        const int c0 = kp + seg;
        float v[8];
        if (c0 + 8 <= H_) {
#pragma unroll
            for (int j = 0; j < 8; j += 2) {
                const float2 t2 = *(const float2*)(xr + c0 + j);  // 8B aligned
                v[j] = t2.x; v[j + 1] = t2.y;
            }
        } else {
#pragma unroll
            for (int j = 0; j < 8; j++) v[j] = (c0 + j < H_) ? xr[c0 + j] : 0.f;
        }
        short8 a_h, a_l;
#pragma unroll
        for (int j = 0; j < 8; j++) {
            u16 hi, lo; split2(v[j], hi, lo);
            a_h[j] = (short)hi;
            a_l[j] = (short)lo;
        }
        const short8 bch = *(const short8*)(wch + kp);
        const short8 bcl = *(const short8*)(wcl + kp);
        const short8 bhh = *(const short8*)(whh + kp);
        const short8 bhl = *(const short8*)(whl + kp);
        accC = __builtin_amdgcn_mfma_f32_32x32x16_bf16(a_h, bch, accC, 0, 0, 0);
        accH = __builtin_amdgcn_mfma_f32_32x32x16_bf16(a_h, bhh, accH, 0, 0, 0);
        accC = __builtin_amdgcn_mfma_f32_32x32x16_bf16(a_l, bch, accC, 0, 0, 0);
        accH = __builtin_amdgcn_mfma_f32_32x32x16_bf16(a_l, bhh, accH, 0, 0, 0);
        accC = __builtin_amdgcn_mfma_f32_32x32x16_bf16(a_h, bcl, accC, 0, 0, 0);
        accH = __builtin_amdgcn_mfma_f32_32x32x16_bf16(a_h, bhl, accH, 0, 0, 0);
    }
}

// ---- fused GEMM + cell update; block = 4 waves = 64m x 64n (x2 c/h) ----
// grid: (16 [n, padded for XCD clustering], nodes, 4 [m])
template <bool STAGE1>
__global__ __launch_bounds__(256) void gemm_kern(
    const u16* __restrict__ WH, const u16* __restrict__ WL,
    u16* __restrict__ SH, u16* __restrict__ SL,
    const float* __restrict__ Xt, int base)
{
    if (blockIdx.x >= 14) return;           // padded n-grid
    const int lane = threadIdx.x & 63;
    const int wv   = threadIdx.x >> 6;
    const int m0 = blockIdx.z * 64 + (wv & 1) * 32;
    const int n0 = blockIdx.x * 64 + (wv >> 1) * 32;
    const int r31 = lane & 31;
    const int seg = (lane >> 5) << 3;
    const int colB = n0 + r31;
    const int rc = colB;                    // c-part weight row (<= 895 < 1700, safe)
    const int rh = min(850 + colB, 1699);   // h-part weight row, clamped

    int pred, act, wi, outp;
    if (STAGE1) { pred = 9; act = 0; wi = 0; outp = 0; }
    else {
        const int node = base + blockIdx.y;
        pred = PRED[node]; act = ACTID[node];
        wi = 2 + node; outp = node + 1;
    }

    floatx16 accC, accH;
#pragma unroll
    for (int i = 0; i < 16; i++) { accC[i] = 0.f; accH[i] = 0.f; }

    if (STAGE1) {
        kloop_x(Xt, WH, WL, m0, rc, rh, r31, seg, accC, accH);
        kloop_planes(SH + 9 * (size_t)PS, SL + 9 * (size_t)PS,
                     WH + (size_t)WMS, WL + (size_t)WMS,
                     m0, rc, rh, r31, seg, accC, accH);
    } else {
        kloop_planes(SH + (size_t)pred * PS, SL + (size_t)pred * PS,
                     WH + (size_t)wi * WMS, WL + (size_t)wi * WMS,
                     m0, rc, rh, r31, seg, accC, accH);
    }

    // epilogue: C/D layout col=lane&31, row=(reg&3)+8*(reg>>2)+4*(lane>>5)
    if (colB < H_) {
        const u16* ph = SH + (size_t)pred * PS;
        const u16* pl = SL + (size_t)pred * PS;
        u16* oh = SH + (size_t)outp * PS;
        u16* ol = SL + (size_t)outp * PS;
        const int rbase = m0 + ((lane >> 5) << 2);
#pragma unroll
        for (int r = 0; r < 16; r++) {
            const int row = rbase + (r & 3) + ((r >> 2) << 3);
            const size_t off = (size_t)row * SP + colB;
            const float s  = b2f(ph[off]) + b2f(pl[off]);
            const float hv = actf(act, accH[r]);
            const float o  = s + sigf(accC[r]) * (hv - s);
            u16 hi, lo; split2(o, hi, lo);
            oh[off] = hi; ol[off] = lo;
        }
    }
}

// ---- finalize: h = mean(s1..s8), write plane 9 + fp32 output ----
__global__ __launch_bounds__(256) void finalize_kern(
    u16* __restrict__ SH, u16* __restrict__ SL,
    float* __restrict__ OUT, float* __restrict__ OUT2)
{
    const int idx = blockIdx.x * 256 + threadIdx.x;   // exactly BH
    const int row = idx / H_, col = idx % H_;
    const size_t off = (size_t)row * SP + col;
    float s = 0.f;
#pragma unroll
    for (int p = 1; p <= 8; p++)
        s += b2f(SH[(size_t)p * PS + off]) + b2f(SL[(size_t)p * PS + off]);
    s *= 0.125f;
    u16 hi, lo; split2(s, hi, lo);
    SH[9 * (size_t)PS + off] = hi;
    SL[9 * (size_t)PS + off] = lo;
    OUT[idx] = s;
    if (OUT2) OUT2[idx] = s;
}

extern "C" void kernel_launch(void* const* d_in, const int* in_sizes, int n_in,
                              void* d_out, int out_size, void* d_ws, size_t ws_size,
                              hipStream_t stream) {
    const float* X   = (const float*)d_in[0];  // [128, 256, 850]
    const float* HID = (const float*)d_in[1];  // [1, 256, 850]
    const float* W0  = (const float*)d_in[2];  // [1700, 1700]
    const float* WS  = (const float*)d_in[3];  // [8, 850, 1700]

    // workspace: WH/WL (10 matrices each) + SH/SL (10 state planes each) ~ 67.6 MB
    u16* WH = (u16*)d_ws;
    u16* WL = WH + (size_t)10 * WMS;
    u16* SH = WL + (size_t)10 * WMS;
    u16* SL = SH + (size_t)10 * PS;

    float* OUT = (float*)d_out;

    transpose_w<<<dim3(14, 27, 10), 256, 0, stream>>>(W0, WS, WH, WL);
    init_kern<<<PS / 256, 256, 0, stream>>>(HID, SH, SL);
    zpad_kern<<<126, 256, 0, stream>>>(SH, SL);

    for (int t = 0; t < T_; t++) {
        gemm_kern<true ><<<dim3(16, 1, 4), 256, 0, stream>>>(WH, WL, SH, SL,
                                                             X + (size_t)t * BH, 0);
        gemm_kern<false><<<dim3(16, 2, 4), 256, 0, stream>>>(WH, WL, SH, SL, nullptr, 0);
        gemm_kern<false><<<dim3(16, 4, 4), 256, 0, stream>>>(WH, WL, SH, SL, nullptr, 2);
        gemm_kern<false><<<dim3(16, 2, 4), 256, 0, stream>>>(WH, WL, SH, SL, nullptr, 6);
        finalize_kern<<<850, 256, 0, stream>>>(
            SH, SL, OUT + (size_t)t * BH,
            (t == T_ - 1) ? (OUT + (size_t)T_ * BH) : (float*)nullptr);
    }
}